// Round 12
// baseline (180.845 us; speedup 1.0000x reference)
//
#include <hip/hip_runtime.h>

// Problem: B=16,C=64,H=32,W=32 -> N=16384 tokens; K=8192 codes.
#define DECAYF 0.99f
#define OMDF   0.01f
#define TAU    3.5e-2f   // fp16 screen: ~9-sigma pairwise (sigma~3.8e-3); candidate fixup exact f32

typedef unsigned int u32;
typedef unsigned long long u64;
typedef __attribute__((ext_vector_type(8))) _Float16 f16x8;  // 8 fp16 (4 VGPRs)
typedef __attribute__((ext_vector_type(4))) float f32x4;     // MFMA 16x16 acc

// ws layout (bytes). High-water = 3702788.
// zfrag (2 MB, fp16 z_e in 16x16 A-frag order) lives in the out0 output
// region: written by k_prep, read by k_argmin, overwritten by k_gather.
// IDX overlays EFRAG head (efrag dead after k_argmin; stream-ordered).
// CSR arrays live in [1081344, 2129920) -- free (efrag is only 1 MB).
#define EN_OFF     0              // en[8192] f32: 0.5*||e||^2
#define EFRAG_OFF  32768          // 1 MB frag-ordered fp16 emb (128 B/code)
#define IDX_OFF    32768          // i32 [16384] final indices   (overlay)
#define CNT8K_OFF  1081344        // i32 [8192] per-code token counts
#define OFFS_OFF   1114112        // i32 [8192] CSR offsets (stable)
#define FILLP_OFF  1146880        // i32 [8192] CSR fill cursors (mutable)
#define TOKL_OFF   1179648        // i32 [16384] CSR token list
#define BEST1_OFF  2129920        // u64 [8][16384] per-(slice,token) best (enc)
#define BEST2_OFF  3178496        // f32 [8][16384] per-(slice,token) 2nd-best
#define NSUM_OFF   3702784        // f32 nsum (0.99*sum(cs_in))

__device__ __forceinline__ u64 enc_pair(float s, int idx) {
  u32 u = __float_as_uint(s);
  u = (u & 0x80000000u) ? ~u : (u | 0x80000000u);   // order-preserving
  return ((u64)u << 32) | (u32)(~idx);              // ~idx: ties -> min idx
}
__device__ __forceinline__ float dec_score(u64 e) {
  u32 u = (u32)(e >> 32);
  u = (u & 0x80000000u) ? (u & 0x7fffffffu) : ~u;
  return __uint_as_float(u);
}
__device__ __forceinline__ int dec_idx(u64 e) { return (int)(~(u32)e); }
__device__ __forceinline__ unsigned short f2h(float f) {  // f32 -> fp16 RNE
  union { _Float16 h; unsigned short u; } v;
  v.h = (_Float16)f;
  return v.u;
}
// exact f32 chain (identical FMA order across screen/fixup uses)
__device__ __forceinline__ float exact_dot(const float* __restrict__ sx,
                                           const float* __restrict__ emb, int k) {
  const float4* e = (const float4*)(emb + (size_t)k * 64);
  float a = 0.f;
#pragma unroll
  for (int q = 0; q < 16; ++q) {
    float4 v = e[q];
    a = fmaf(sx[4 * q],     v.x, a);
    a = fmaf(sx[4 * q + 1], v.y, a);
    a = fmaf(sx[4 * q + 2], v.z, a);
    a = fmaf(sx[4 * q + 3], v.w, a);
  }
  return a;
}

// ---- fused prep: [0,512) eprep | [512,1031) init | 1031 solo | [1032,1160) zprep
__global__ __launch_bounds__(256) void k_prep(const float* __restrict__ emb,
                                              const float* __restrict__ cs_in,
                                              const float* __restrict__ avg_in,
                                              const float* __restrict__ z_e,
                                              float* __restrict__ en,
                                              unsigned char* __restrict__ efrag,
                                              unsigned char* __restrict__ zfrag,
                                              float* __restrict__ out4,
                                              float* __restrict__ out5,
                                              float* __restrict__ nsum,
                                              int* __restrict__ cnt8k) {
  __shared__ float warr[4];
  __shared__ float sx[64][129];       // zprep transpose buffer (33 KB, padded)
  int bid = blockIdx.x;
  int t = threadIdx.x;
  if (bid < 512) {                    // ---- eprep: 131072 float4s of emb
    int tid = bid * 256 + t;
    int k = tid >> 4, q = tid & 15;   // code k, channels 4q..4q+3
    float4 v = ((const float4*)emb)[tid];
    ushort4 hv;
    hv.x = f2h(v.x); hv.y = f2h(v.y); hv.z = f2h(v.z); hv.w = f2h(v.w);
    // tile=k>>4, col=k&15, frag=q>>3, kib=(q>>1)&3, half=q&1
    size_t off = (size_t)(k >> 4) * 2048 + (size_t)(q >> 3) * 1024
               + (size_t)((q >> 1) & 3) * 256 + (size_t)(k & 15) * 16
               + (size_t)(q & 1) * 8;
    *(ushort4*)(efrag + off) = hv;
    float s = v.x * v.x + v.y * v.y + v.z * v.z + v.w * v.w;
    s += __shfl_xor(s, 1, 16);
    s += __shfl_xor(s, 2, 16);
    s += __shfl_xor(s, 4, 16);
    s += __shfl_xor(s, 8, 16);
    if (q == 0) en[k] = 0.5f * s;
  } else if (bid < 1031) {            // ---- init avg: 131072 float4s
    int tid = (bid - 512) * 256 + t;
    if (tid < 131072) {
      float4 v = ((const float4*)avg_in)[tid];
      v.x *= DECAYF; v.y *= DECAYF; v.z *= DECAYF; v.w *= DECAYF;
      ((float4*)out5)[tid] = v;
    }
  } else if (bid == 1031) {           // ---- solo: cs scale + sum + zero cnt
    float s = 0.f;
#pragma unroll
    for (int q = 0; q < 8; ++q) {
      int idx = q * 256 + t;                   // 2048 float4s of cluster_size
      float4 v = ((const float4*)cs_in)[idx];
      v.x *= DECAYF; v.y *= DECAYF; v.z *= DECAYF; v.w *= DECAYF;
      ((float4*)out4)[idx] = v;
      s += v.x + v.y + v.z + v.w;              // already x0.99
      ((int4*)cnt8k)[idx] = make_int4(0, 0, 0, 0);   // zero counts (2048 int4)
    }
    s += __shfl_xor(s, 1, 64);
    s += __shfl_xor(s, 2, 64);
    s += __shfl_xor(s, 4, 64);
    s += __shfl_xor(s, 8, 64);
    s += __shfl_xor(s, 16, 64);
    s += __shfl_xor(s, 32, 64);
    if ((t & 63) == 0) warr[t >> 6] = s;
    __syncthreads();
    if (t == 0) *nsum = warr[0] + warr[1] + warr[2] + warr[3];
  } else {                            // ---- zprep: 128 blocks x 128 tokens
    int n0 = (bid - 1032) * 128;
    int b = n0 >> 10, hwb = n0 & 1023;
#pragma unroll
    for (int r = 0; r < 8; ++r) {
      int g = r * 256 + t;                     // 0..2047 float4s, coalesced
      int c = g >> 5, f4 = g & 31;
      float4 v = *(const float4*)(z_e + ((size_t)b << 16) + ((size_t)c << 10)
                                  + hwb + f4 * 4);
      sx[c][f4 * 4 + 0] = v.x;
      sx[c][f4 * 4 + 1] = v.y;
      sx[c][f4 * 4 + 2] = v.z;
      sx[c][f4 * 4 + 3] = v.w;
    }
    __syncthreads();
#pragma unroll
    for (int r = 0; r < 4; ++r) {
      int id = r * 256 + t;                    // 0..1023
      int nl = id & 127, k = id >> 7;          // token-local, cell
      int n = n0 + nl;
      unsigned short u[8];
#pragma unroll
      for (int j = 0; j < 8; ++j) u[j] = f2h(sx[k * 8 + j][nl]);
      size_t off = (size_t)(n >> 4) * 2048 + (size_t)(k >> 2) * 1024
                 + (size_t)(k & 3) * 256 + (size_t)(n & 15) * 16;
      *(ushort4*)(zfrag + off)     = make_ushort4(u[0], u[1], u[2], u[3]);
      *(ushort4*)(zfrag + off + 8) = make_ushort4(u[4], u[5], u[6], u[7]);
    }
  }
}

// ---- MFMA argmin (R8-proven config): 16x16x32 fp16; 1 tile/wave; LDS dbuf
// grid 2048 = 256 token-groups (64 tokens) x 8 K-slices (1024 codes)
__global__ __launch_bounds__(256) void k_argmin_mfma(
    const unsigned char* __restrict__ zfrag,
    const unsigned char* __restrict__ efrag,
    const float* __restrict__ en, u64* __restrict__ best1,
    float* __restrict__ best2) {
  alignas(16) __shared__ unsigned char sbuf[2][8192];   // dbuf: 4 tiles each
  __shared__ float sen[1024];                           // 0.5*||e||^2 slice
  const int tb = blockIdx.x >> 3;            // token group (64 tokens)
  const int sl = blockIdx.x & 7;             // K-slice (1024 codes)
  const int wave = threadIdx.x >> 6, lane = threadIdx.x & 63;
  const int col = lane & 15, g4 = lane >> 4;
  const int token0 = tb * 64 + wave * 16;
  const int scb = sl << 10;

  // en slice -> LDS (1024 f32 = 256 float4)
  ((float4*)sen)[threadIdx.x] = ((const float4*)(en + scb))[threadIdx.x];

  // A fragments: 1 token-tile x 2 K-frags, direct vector loads from zfrag
  f16x8 a0, a1;
  {
    const unsigned char* zb = zfrag + ((size_t)(tb * 4 + wave)) * 2048
                            + (size_t)g4 * 256 + (size_t)col * 16;
    a0 = *(const f16x8*)(zb);
    a1 = *(const f16x8*)(zb + 1024);
  }
  float b1[4], b2[4];
#pragma unroll
  for (int r = 0; r < 4; ++r) { b1[r] = -3.0e38f; b2[r] = -3.0e38f; }

  const unsigned char* gbase0 = efrag + (size_t)scb * 128;   // 128 B/code
  auto stage = [&](int ib, int buf) {
    const unsigned char* g = gbase0 + (size_t)ib * 8192 + (size_t)wave * 2048;
#pragma unroll
    for (int it = 0; it < 2; ++it) {
      __builtin_amdgcn_global_load_lds(
          (const __attribute__((address_space(1))) u32*)(g + it * 1024 + lane * 16),
          (__attribute__((address_space(3))) u32*)(&sbuf[buf][wave * 2048 + it * 1024]),
          16, 0, 0);
    }
  };
  stage(0, 0);                                // prologue
  for (int ib = 0; ib < 16; ++ib) {
    __syncthreads();                          // drains vmcnt -> stage(ib) done
    if (ib < 15) stage(ib + 1, (ib + 1) & 1); // prefetch overlaps compute(ib)
    const unsigned char* sb0 = &sbuf[ib & 1][0];
#pragma unroll
    for (int ct = 0; ct < 4; ++ct) {
      const int t = ib * 4 + ct;              // 0..63 tile id in slice
      const float negen = -sen[t * 16 + col]; // this lane's code column
      f16x8 bf0 = *(const f16x8*)(sb0 + ct * 2048 + lane * 16);
      f16x8 bf1 = *(const f16x8*)(sb0 + ct * 2048 + 1024 + lane * 16);
      f32x4 acc;
#pragma unroll
      for (int r = 0; r < 4; ++r) acc[r] = negen;   // fold -0.5||e||^2 into C
      acc = __builtin_amdgcn_mfma_f32_16x16x32_f16(a0, bf0, acc, 0, 0, 0);
      acc = __builtin_amdgcn_mfma_f32_16x16x32_f16(a1, bf1, acc, 0, 0, 0);
      const u32 emb6 = (u32)(63 - t);         // tile idx in low 6 mantissa bits
#pragma unroll
      for (int r = 0; r < 4; ++r) {
        float f0 = __uint_as_float((__float_as_uint(acc[r]) & 0xFFFFFFC0u) | emb6);
        b2[r] = __builtin_amdgcn_fmed3f(f0, b1[r], b2[r]);
        b1[r] = fmaxf(b1[r], f0);
      }
    }
  }
  // reduce across the 16 code-columns (lanes within each 16-lane group)
  int mi[4];
#pragma unroll
  for (int r = 0; r < 4; ++r) mi[r] = col;
#pragma unroll
  for (int st = 1; st < 16; st <<= 1) {
#pragma unroll
    for (int r = 0; r < 4; ++r) {
      float ob1 = __shfl_xor(b1[r], st, 64);
      float ob2 = __shfl_xor(b2[r], st, 64);
      int omi = __shfl_xor(mi[r], st, 64);
      bool ogt = ob1 > b1[r];            // strict: equal -> quantized tie -> fixup
      b2[r] = fmaxf(fminf(b1[r], ob1), fmaxf(b2[r], ob2));
      mi[r] = ogt ? omi : mi[r];
      b1[r] = fmaxf(b1[r], ob1);
    }
  }
  if (col == 0) {   // lanes 0,16,32,48: 4 token-rows each; [sl][token] layout
#pragma unroll
    for (int r = 0; r < 4; ++r) {
      int token = token0 + g4 * 4 + r;        // C/D row map [m89]
      int t = 63 - (int)(__float_as_uint(b1[r]) & 63u);
      int gcode = scb + t * 16 + mi[r];
      best1[(size_t)sl * 16384 + token] = enc_pair(b1[r], gcode);
      best2[(size_t)sl * 16384 + token] = b2[r];
    }
  }
}

// ---- merged resolve + candidate fixup + CSR count: block = 64 tokens -----
__global__ __launch_bounds__(256) void k_resfix(const float* __restrict__ z_e,
                                                const float* __restrict__ emb,
                                                const float* __restrict__ en,
                                                const u64* __restrict__ best1,
                                                const float* __restrict__ best2,
                                                int* __restrict__ idxa,
                                                int* __restrict__ cnt8k) {
  __shared__ float sxr[64];
  __shared__ int sidx[64];
  __shared__ int flist[64];
  __shared__ float fth[64];
  __shared__ int nflag;
  __shared__ u32 fmask;
  __shared__ u64 red;
  int t = threadIdx.x;
  int n0 = blockIdx.x * 64;
  if (t == 0) nflag = 0;
  __syncthreads();
  if (t < 64) {
    int n = n0 + t;
    u64 e[8];
#pragma unroll
    for (int s = 0; s < 8; ++s) e[s] = best1[(size_t)s * 16384 + n];
    u64 top = e[0];
#pragma unroll
    for (int s = 1; s < 8; ++s) top = e[s] > top ? e[s] : top;
    float second = -3.0e38f;
#pragma unroll
    for (int s = 0; s < 8; ++s)
      second = fmaxf(second, best2[(size_t)s * 16384 + n]);
#pragma unroll
    for (int s = 0; s < 8; ++s)
      if (e[s] != top) second = fmaxf(second, dec_score(e[s]));
    idxa[n] = dec_idx(top);
    sidx[t] = dec_idx(top);
    if (dec_score(top) - second < TAU) {
      int p = atomicAdd(&nflag, 1);
      flist[p] = n;
      fth[p] = dec_score(top);
    }
  }
  __syncthreads();
  int nf = nflag;
  for (int i = 0; i < nf; ++i) {
    int n = flist[i];
    float theta = fth[i] - TAU;
    if (t == 0) { fmask = 0; red = 0ull; }
    if (t < 64) {
      sxr[t] = z_e[((size_t)(n >> 10) << 16) + ((size_t)t << 10) + (n & 1023)];
    }
    __syncthreads();
    u64 myb = 0ull;
    if (t < 8) {
      u64 es = best1[(size_t)t * 16384 + n];
      if (best2[(size_t)t * 16384 + n] >= theta) atomicOr(&fmask, 1u << t);
      if (dec_score(es) >= theta) {        // candidate: exact dot
        int k = dec_idx(es);
        float a = exact_dot(sxr, emb, k) - en[k];
        myb = enc_pair(a, k);
      }
    }
    __syncthreads();
    u32 fm = fmask;
    while (fm) {                           // rare: full 1024-code slice rescan
      int s = __ffs(fm) - 1;
      fm &= fm - 1;
      int k0 = (s << 10) + t;              // 4 codes: +0,+256,+512,+768
      float a0 = exact_dot(sxr, emb, k0)       - en[k0];
      float a1 = exact_dot(sxr, emb, k0 + 256) - en[k0 + 256];
      float a2 = exact_dot(sxr, emb, k0 + 512) - en[k0 + 512];
      float a3 = exact_dot(sxr, emb, k0 + 768) - en[k0 + 768];
      u64 m0 = enc_pair(a0, k0),       m1 = enc_pair(a1, k0 + 256);
      u64 m2 = enc_pair(a2, k0 + 512), m3 = enc_pair(a3, k0 + 768);
      u64 ma = m0 > m1 ? m0 : m1, mb = m2 > m3 ? m2 : m3;
      u64 mm = ma > mb ? ma : mb;
      myb = mm > myb ? mm : myb;
    }
    if (myb) atomicMax(&red, myb);
    __syncthreads();
    if (t == 0) {
      idxa[n] = dec_idx(red);
      sidx[n - n0] = dec_idx(red);
    }
    __syncthreads();
  }
  // CSR count: one increment per token (final indices)
  if (t < 64) atomicAdd(&cnt8k[sidx[t]], 1);
}

// ---- exclusive prefix scan over 8192 counts (one block) ------------------
__global__ __launch_bounds__(256) void k_scan(const int* __restrict__ cnt8k,
                                              int* __restrict__ offs,
                                              int* __restrict__ fillp) {
  __shared__ int part[256];
  int t = threadIdx.x;
  int loc[32];
  int s = 0;
#pragma unroll
  for (int i = 0; i < 32; ++i) {        // sequential exclusive within chunk
    loc[i] = s;
    s += cnt8k[t * 32 + i];
  }
  part[t] = s;
  __syncthreads();
  for (int st = 1; st < 256; st <<= 1) {   // inclusive scan of chunk sums
    int add = (t >= st) ? part[t - st] : 0;
    __syncthreads();
    part[t] += add;
    __syncthreads();
  }
  int base = part[t] - s;               // exclusive chunk base
#pragma unroll
  for (int i = 0; i < 32; ++i) {
    int o = base + loc[i];
    offs[t * 32 + i]  = o;
    fillp[t * 32 + i] = o;
  }
}

// ---- CSR fill: token n -> slot in its code's segment ---------------------
__global__ __launch_bounds__(256) void k_fill(const int* __restrict__ idxa,
                                              int* __restrict__ fillp,
                                              int* __restrict__ tokl) {
  int n = blockIdx.x * 256 + threadIdx.x;   // 16384
  int idx = idxa[n];
  int pos = atomicAdd(&fillp[idx], 1);
  tokl[pos] = n;
}

// ---- gather z_q / z_q_st / indices + per-code EMA update (no atomics) ----
__global__ __launch_bounds__(256) void k_gather(const float* __restrict__ z_e,
                                                const float* __restrict__ emb,
                                                const int* __restrict__ idxa,
                                                const int* __restrict__ cnt8k,
                                                const int* __restrict__ offs,
                                                const int* __restrict__ tokl,
                                                float* __restrict__ out0,
                                                float* __restrict__ out1,
                                                float* __restrict__ out2,
                                                float* __restrict__ out5) {
  int tid = blockIdx.x * 256 + threadIdx.x;   // 262144 = 16 b x 64 c x 256 hw4
  {   // ---- phase A: gather (proven mapping)
    int hw4 = tid & 255;
    int c   = (tid >> 8) & 63;
    int b   = tid >> 14;
    int n0  = (b << 10) + (hw4 << 2);
    size_t off = ((size_t)b << 16) + ((size_t)c << 10) + ((size_t)hw4 << 2);
    float4 z = *(const float4*)(z_e + off);
    int i0 = idxa[n0], i1 = idxa[n0 + 1], i2 = idxa[n0 + 2], i3 = idxa[n0 + 3];
    float4 q;
    q.x = emb[(size_t)i0 * 64 + c];
    q.y = emb[(size_t)i1 * 64 + c];
    q.z = emb[(size_t)i2 * 64 + c];
    q.w = emb[(size_t)i3 * 64 + c];
    float4 st;
    st.x = z.x + (q.x - z.x);
    st.y = z.y + (q.y - z.y);
    st.z = z.z + (q.z - z.z);
    st.w = z.w + (q.w - z.w);
    *(float4*)(out2 + off) = q;
    *(float4*)(out0 + off) = st;
    if (c == 0) {
      float4 f = make_float4((float)i0, (float)i1, (float)i2, (float)i3);
      *(float4*)(out1 + n0) = f;
    }
  }
  {   // ---- phase B: per-code EMA avg update; wave owns 2 codes (exclusive)
    int wv = blockIdx.x * 4 + (threadIdx.x >> 6);   // 0..4095
    int lane = threadIdx.x & 63;                    // lane = channel
#pragma unroll
    for (int rep = 0; rep < 2; ++rep) {
      int k = wv * 2 + rep;                         // 0..8191
      int cnt = cnt8k[k];
      int o = offs[k];
      float sum = 0.f;
      for (int j = 0; j < cnt; ++j) {
        int n = tokl[o + j];
        sum += z_e[((size_t)(n >> 10) << 16) + ((size_t)lane << 10) + (n & 1023)];
      }
      if (cnt > 0) {
        size_t oi = (size_t)k * 64 + lane;
        out5[oi] = fmaf(OMDF, sum, out5[oi]);
      }
    }
  }
}

// ---- new_cluster (exact) + new_embedding = avg / cs ----------------------
__global__ __launch_bounds__(256) void k_final(float* __restrict__ out4,
                                               const float* __restrict__ out5,
                                               const float* __restrict__ nsum,
                                               const int* __restrict__ cnt8k,
                                               float* __restrict__ out3) {
  int tid = blockIdx.x * 256 + threadIdx.x;
  int k = tid >> 4;
  float ncsf = fmaf(OMDF, (float)cnt8k[k], out4[k]);   // 0.99cs + 0.01*count
  double nn  = (double)*nsum + 163.84;                 // + 0.01*16384
  double cs  = ((double)ncsf + 1e-5) / (nn + 8192.0 * 1e-5) * nn;
  float inv  = (float)(1.0 / cs);
  float4 v = ((const float4*)out5)[tid];
  v.x *= inv; v.y *= inv; v.z *= inv; v.w *= inv;
  ((float4*)out3)[tid] = v;
  if ((tid & 15) == 0) out4[k] = ncsf;
}

extern "C" void kernel_launch(void* const* d_in, const int* in_sizes, int n_in,
                              void* d_out, int out_size, void* d_ws, size_t ws_size,
                              hipStream_t stream) {
  const float* z_e    = (const float*)d_in[0];
  const float* emb    = (const float*)d_in[1];
  const float* cs_in  = (const float*)d_in[2];
  const float* avg_in = (const float*)d_in[3];

  float* out  = (float*)d_out;
  float* out0 = out;                    // z_q_st        1048576
  float* out1 = out0 + 1048576;         // indices(f32)  16384
  float* out2 = out1 + 16384;           // z_q           1048576
  float* out3 = out2 + 1048576;         // new_embedding 524288
  float* out4 = out3 + 524288;          // new_cluster   8192
  float* out5 = out4 + 8192;            // new_emb_avg   524288

  char* ws = (char*)d_ws;
  float* en            = (float*)(ws + EN_OFF);
  unsigned char* efrag = (unsigned char*)(ws + EFRAG_OFF);
  int* idxa            = (int*)(ws + IDX_OFF);
  int* cnt8k           = (int*)(ws + CNT8K_OFF);
  int* offs            = (int*)(ws + OFFS_OFF);
  int* fillp           = (int*)(ws + FILLP_OFF);
  int* tokl            = (int*)(ws + TOKL_OFF);
  u64* best1           = (u64*)(ws + BEST1_OFF);
  float* best2         = (float*)(ws + BEST2_OFF);
  float* nsum          = (float*)(ws + NSUM_OFF);
  unsigned char* zfrag = (unsigned char*)out0;   // 2 MB scratch in out0 region

  k_prep       <<<1160, 256, 0, stream>>>(emb, cs_in, avg_in, z_e, en, efrag,
                                          zfrag, out4, out5, nsum, cnt8k);
  k_argmin_mfma<<<2048, 256, 0, stream>>>(zfrag, efrag, en, best1, best2);
  k_resfix     <<<256,  256, 0, stream>>>(z_e, emb, en, best1, best2, idxa, cnt8k);
  k_scan       <<<1,    256, 0, stream>>>(cnt8k, offs, fillp);
  k_fill       <<<64,   256, 0, stream>>>(idxa, fillp, tokl);
  k_gather     <<<1024, 256, 0, stream>>>(z_e, emb, idxa, cnt8k, offs, tokl,
                                          out0, out1, out2, out5);
  k_final      <<<512,  256, 0, stream>>>(out4, out5, nsum, cnt8k, out3);
}

// Round 14
// 154.668 us; speedup vs baseline: 1.1692x; 1.1692x over previous
//
#include <hip/hip_runtime.h>

// Problem: B=16,C=64,H=32,W=32 -> N=16384 tokens; K=8192 codes.
#define DECAYF 0.99f
#define OMDF   0.01f
#define TAU    3.5e-2f   // fp16 screen: ~9-sigma pairwise (sigma~3.8e-3); candidate fixup exact f32

typedef unsigned int u32;
typedef unsigned long long u64;
typedef __attribute__((ext_vector_type(8))) _Float16 f16x8;  // 8 fp16 (4 VGPRs)
typedef __attribute__((ext_vector_type(4))) float f32x4;     // MFMA 16x16 acc

// ws layout (bytes). High-water = 3702788.
// zfrag (2 MB, fp16 z_e in 16x16 A-frag order) lives in the out0 output
// region: written by k_prep, read by k_argmin, overwritten by k_gather.
// IDX overlays EFRAG head (efrag dead after k_argmin; stream-ordered).
#define EN_OFF     0              // en[8192] f32: 0.5*||e||^2
#define EFRAG_OFF  32768          // 1 MB frag-ordered fp16 emb (128 B/code)
#define IDX_OFF    32768          // i32 [16384] final indices   (overlay)
#define BEST1_OFF  2129920        // u64 [8][16384] per-(slice,token) best (enc)
#define BEST2_OFF  3178496        // f32 [8][16384] per-(slice,token) 2nd-best
#define NSUM_OFF   3702784        // f32 nsum (0.99*sum(cs_in))

__device__ __forceinline__ u64 enc_pair(float s, int idx) {
  u32 u = __float_as_uint(s);
  u = (u & 0x80000000u) ? ~u : (u | 0x80000000u);   // order-preserving
  return ((u64)u << 32) | (u32)(~idx);              // ~idx: ties -> min idx
}
__device__ __forceinline__ float dec_score(u64 e) {
  u32 u = (u32)(e >> 32);
  u = (u & 0x80000000u) ? (u & 0x7fffffffu) : ~u;
  return __uint_as_float(u);
}
__device__ __forceinline__ int dec_idx(u64 e) { return (int)(~(u32)e); }
__device__ __forceinline__ unsigned short f2h(float f) {  // f32 -> fp16 RNE
  union { _Float16 h; unsigned short u; } v;
  v.h = (_Float16)f;
  return v.u;
}
// exact f32 chain (identical FMA order across screen/fixup uses)
__device__ __forceinline__ float exact_dot(const float* __restrict__ sx,
                                           const float* __restrict__ emb, int k) {
  const float4* e = (const float4*)(emb + (size_t)k * 64);
  float a = 0.f;
#pragma unroll
  for (int q = 0; q < 16; ++q) {
    float4 v = e[q];
    a = fmaf(sx[4 * q],     v.x, a);
    a = fmaf(sx[4 * q + 1], v.y, a);
    a = fmaf(sx[4 * q + 2], v.z, a);
    a = fmaf(sx[4 * q + 3], v.w, a);
  }
  return a;
}

// ---- fused prep: [0,512) eprep | [512,1031) init | 1031 solo | [1032,1288) zprep
// zprep: 256 blocks x 64 tokens; 16.6 KB LDS (was 33 KB -> 2x occupancy)
__global__ __launch_bounds__(256) void k_prep(const float* __restrict__ emb,
                                              const float* __restrict__ cs_in,
                                              const float* __restrict__ avg_in,
                                              const float* __restrict__ z_e,
                                              float* __restrict__ en,
                                              unsigned char* __restrict__ efrag,
                                              unsigned char* __restrict__ zfrag,
                                              float* __restrict__ out4,
                                              float* __restrict__ out5,
                                              float* __restrict__ nsum) {
  __shared__ float warr[4];
  __shared__ float sx[64][65];        // zprep transpose buffer (16.6 KB, padded)
  int bid = blockIdx.x;
  int t = threadIdx.x;
  if (bid < 512) {                    // ---- eprep: 131072 float4s of emb
    int tid = bid * 256 + t;
    int k = tid >> 4, q = tid & 15;   // code k, channels 4q..4q+3
    float4 v = ((const float4*)emb)[tid];
    ushort4 hv;
    hv.x = f2h(v.x); hv.y = f2h(v.y); hv.z = f2h(v.z); hv.w = f2h(v.w);
    // tile=k>>4, col=k&15, frag=q>>3, kib=(q>>1)&3, half=q&1
    size_t off = (size_t)(k >> 4) * 2048 + (size_t)(q >> 3) * 1024
               + (size_t)((q >> 1) & 3) * 256 + (size_t)(k & 15) * 16
               + (size_t)(q & 1) * 8;
    *(ushort4*)(efrag + off) = hv;
    float s = v.x * v.x + v.y * v.y + v.z * v.z + v.w * v.w;
    s += __shfl_xor(s, 1, 16);
    s += __shfl_xor(s, 2, 16);
    s += __shfl_xor(s, 4, 16);
    s += __shfl_xor(s, 8, 16);
    if (q == 0) en[k] = 0.5f * s;
  } else if (bid < 1031) {            // ---- init avg: 131072 float4s
    int tid = (bid - 512) * 256 + t;
    if (tid < 131072) {
      float4 v = ((const float4*)avg_in)[tid];
      v.x *= DECAYF; v.y *= DECAYF; v.z *= DECAYF; v.w *= DECAYF;
      ((float4*)out5)[tid] = v;
    }
  } else if (bid == 1031) {           // ---- solo: cs scale + total sum
    float s = 0.f;
#pragma unroll
    for (int q = 0; q < 8; ++q) {
      int idx = q * 256 + t;                   // 2048 float4s of cluster_size
      float4 v = ((const float4*)cs_in)[idx];
      v.x *= DECAYF; v.y *= DECAYF; v.z *= DECAYF; v.w *= DECAYF;
      ((float4*)out4)[idx] = v;
      s += v.x + v.y + v.z + v.w;              // already x0.99
    }
    s += __shfl_xor(s, 1, 64);
    s += __shfl_xor(s, 2, 64);
    s += __shfl_xor(s, 4, 64);
    s += __shfl_xor(s, 8, 64);
    s += __shfl_xor(s, 16, 64);
    s += __shfl_xor(s, 32, 64);
    if ((t & 63) == 0) warr[t >> 6] = s;
    __syncthreads();
    if (t == 0) *nsum = warr[0] + warr[1] + warr[2] + warr[3];
  } else {                            // ---- zprep: 256 blocks x 64 tokens
    int n0 = (bid - 1032) * 64;
    int b = n0 >> 10, hwb = n0 & 1023;
#pragma unroll
    for (int r = 0; r < 4; ++r) {
      int g = r * 256 + t;                     // 0..1023 float4s, coalesced
      int c = g >> 4, f4 = g & 15;
      float4 v = *(const float4*)(z_e + ((size_t)b << 16) + ((size_t)c << 10)
                                  + hwb + f4 * 4);
      sx[c][f4 * 4 + 0] = v.x;
      sx[c][f4 * 4 + 1] = v.y;
      sx[c][f4 * 4 + 2] = v.z;
      sx[c][f4 * 4 + 3] = v.w;
    }
    __syncthreads();
#pragma unroll
    for (int r = 0; r < 2; ++r) {
      int id = r * 256 + t;                    // 0..511
      int nl = id & 63, k = id >> 6;           // token-local, cell
      int n = n0 + nl;
      unsigned short u[8];
#pragma unroll
      for (int j = 0; j < 8; ++j) u[j] = f2h(sx[k * 8 + j][nl]);
      size_t off = (size_t)(n >> 4) * 2048 + (size_t)(k >> 2) * 1024
                 + (size_t)(k & 3) * 256 + (size_t)(n & 15) * 16;
      *(ushort4*)(zfrag + off)     = make_ushort4(u[0], u[1], u[2], u[3]);
      *(ushort4*)(zfrag + off + 8) = make_ushort4(u[4], u[5], u[6], u[7]);
    }
  }
}

// ---- MFMA argmin (R8-proven config, 44.0 us): 16x16x32 fp16; LDS dbuf ----
// grid 2048 = 256 token-groups (64 tokens) x 8 K-slices (1024 codes)
__global__ __launch_bounds__(256) void k_argmin_mfma(
    const unsigned char* __restrict__ zfrag,
    const unsigned char* __restrict__ efrag,
    const float* __restrict__ en, u64* __restrict__ best1,
    float* __restrict__ best2) {
  alignas(16) __shared__ unsigned char sbuf[2][8192];   // dbuf: 4 tiles each
  __shared__ float sen[1024];                           // 0.5*||e||^2 slice
  const int tb = blockIdx.x >> 3;            // token group (64 tokens)
  const int sl = blockIdx.x & 7;             // K-slice (1024 codes)
  const int wave = threadIdx.x >> 6, lane = threadIdx.x & 63;
  const int col = lane & 15, g4 = lane >> 4;
  const int token0 = tb * 64 + wave * 16;
  const int scb = sl << 10;

  // en slice -> LDS (1024 f32 = 256 float4)
  ((float4*)sen)[threadIdx.x] = ((const float4*)(en + scb))[threadIdx.x];

  // A fragments: 1 token-tile x 2 K-frags, direct vector loads from zfrag
  f16x8 a0, a1;
  {
    const unsigned char* zb = zfrag + ((size_t)(tb * 4 + wave)) * 2048
                            + (size_t)g4 * 256 + (size_t)col * 16;
    a0 = *(const f16x8*)(zb);
    a1 = *(const f16x8*)(zb + 1024);
  }
  float b1[4], b2[4];
#pragma unroll
  for (int r = 0; r < 4; ++r) { b1[r] = -3.0e38f; b2[r] = -3.0e38f; }

  const unsigned char* gbase0 = efrag + (size_t)scb * 128;   // 128 B/code
  auto stage = [&](int ib, int buf) {
    const unsigned char* g = gbase0 + (size_t)ib * 8192 + (size_t)wave * 2048;
#pragma unroll
    for (int it = 0; it < 2; ++it) {
      __builtin_amdgcn_global_load_lds(
          (const __attribute__((address_space(1))) u32*)(g + it * 1024 + lane * 16),
          (__attribute__((address_space(3))) u32*)(&sbuf[buf][wave * 2048 + it * 1024]),
          16, 0, 0);
    }
  };
  stage(0, 0);                                // prologue
  for (int ib = 0; ib < 16; ++ib) {
    __syncthreads();                          // drains vmcnt -> stage(ib) done
    if (ib < 15) stage(ib + 1, (ib + 1) & 1); // prefetch overlaps compute(ib)
    const unsigned char* sb0 = &sbuf[ib & 1][0];
#pragma unroll
    for (int ct = 0; ct < 4; ++ct) {
      const int t = ib * 4 + ct;              // 0..63 tile id in slice
      const float negen = -sen[t * 16 + col]; // this lane's code column
      f16x8 bf0 = *(const f16x8*)(sb0 + ct * 2048 + lane * 16);
      f16x8 bf1 = *(const f16x8*)(sb0 + ct * 2048 + 1024 + lane * 16);
      f32x4 acc;
#pragma unroll
      for (int r = 0; r < 4; ++r) acc[r] = negen;   // fold -0.5||e||^2 into C
      acc = __builtin_amdgcn_mfma_f32_16x16x32_f16(a0, bf0, acc, 0, 0, 0);
      acc = __builtin_amdgcn_mfma_f32_16x16x32_f16(a1, bf1, acc, 0, 0, 0);
      const u32 emb6 = (u32)(63 - t);         // tile idx in low 6 mantissa bits
#pragma unroll
      for (int r = 0; r < 4; ++r) {
        float f0 = __uint_as_float((__float_as_uint(acc[r]) & 0xFFFFFFC0u) | emb6);
        b2[r] = __builtin_amdgcn_fmed3f(f0, b1[r], b2[r]);
        b1[r] = fmaxf(b1[r], f0);
      }
    }
  }
  // reduce across the 16 code-columns (lanes within each 16-lane group)
  int mi[4];
#pragma unroll
  for (int r = 0; r < 4; ++r) mi[r] = col;
#pragma unroll
  for (int st = 1; st < 16; st <<= 1) {
#pragma unroll
    for (int r = 0; r < 4; ++r) {
      float ob1 = __shfl_xor(b1[r], st, 64);
      float ob2 = __shfl_xor(b2[r], st, 64);
      int omi = __shfl_xor(mi[r], st, 64);
      bool ogt = ob1 > b1[r];            // strict: equal -> quantized tie -> fixup
      b2[r] = fmaxf(fminf(b1[r], ob1), fmaxf(b2[r], ob2));
      mi[r] = ogt ? omi : mi[r];
      b1[r] = fmaxf(b1[r], ob1);
    }
  }
  if (col == 0) {   // lanes 0,16,32,48: 4 token-rows each; [sl][token] layout
#pragma unroll
    for (int r = 0; r < 4; ++r) {
      int token = token0 + g4 * 4 + r;        // C/D row map [m89]
      int t = 63 - (int)(__float_as_uint(b1[r]) & 63u);
      int gcode = scb + t * 16 + mi[r];
      best1[(size_t)sl * 16384 + token] = enc_pair(b1[r], gcode);
      best2[(size_t)sl * 16384 + token] = b2[r];
    }
  }
}

// ---- merged resolve + candidate fixup: block = 64 tokens, 8 slices -------
__global__ __launch_bounds__(256) void k_resfix(const float* __restrict__ z_e,
                                                const float* __restrict__ emb,
                                                const float* __restrict__ en,
                                                const u64* __restrict__ best1,
                                                const float* __restrict__ best2,
                                                int* __restrict__ idxa) {
  __shared__ float sxr[64];
  __shared__ int flist[64];
  __shared__ float fth[64];
  __shared__ int nflag;
  __shared__ u32 fmask;
  __shared__ u64 red;
  int t = threadIdx.x;
  int n0 = blockIdx.x * 64;
  if (t == 0) nflag = 0;
  __syncthreads();
  if (t < 64) {
    int n = n0 + t;
    u64 e[8];
#pragma unroll
    for (int s = 0; s < 8; ++s) e[s] = best1[(size_t)s * 16384 + n];
    u64 top = e[0];
#pragma unroll
    for (int s = 1; s < 8; ++s) top = e[s] > top ? e[s] : top;
    float second = -3.0e38f;
#pragma unroll
    for (int s = 0; s < 8; ++s)
      second = fmaxf(second, best2[(size_t)s * 16384 + n]);
#pragma unroll
    for (int s = 0; s < 8; ++s)
      if (e[s] != top) second = fmaxf(second, dec_score(e[s]));
    idxa[n] = dec_idx(top);
    if (dec_score(top) - second < TAU) {
      int p = atomicAdd(&nflag, 1);
      flist[p] = n;
      fth[p] = dec_score(top);
    }
  }
  __syncthreads();
  int nf = nflag;
  for (int i = 0; i < nf; ++i) {
    int n = flist[i];
    float theta = fth[i] - TAU;
    if (t == 0) { fmask = 0; red = 0ull; }
    if (t < 64) {
      sxr[t] = z_e[((size_t)(n >> 10) << 16) + ((size_t)t << 10) + (n & 1023)];
    }
    __syncthreads();
    u64 myb = 0ull;
    if (t < 8) {
      u64 es = best1[(size_t)t * 16384 + n];
      if (best2[(size_t)t * 16384 + n] >= theta) atomicOr(&fmask, 1u << t);
      if (dec_score(es) >= theta) {        // candidate: exact dot
        int k = dec_idx(es);
        float a = exact_dot(sxr, emb, k) - en[k];
        myb = enc_pair(a, k);
      }
    }
    __syncthreads();
    u32 fm = fmask;
    while (fm) {                           // rare: full 1024-code slice rescan
      int s = __ffs(fm) - 1;
      fm &= fm - 1;
      int k0 = (s << 10) + t;              // 4 codes: +0,+256,+512,+768
      float a0 = exact_dot(sxr, emb, k0)       - en[k0];
      float a1 = exact_dot(sxr, emb, k0 + 256) - en[k0 + 256];
      float a2 = exact_dot(sxr, emb, k0 + 512) - en[k0 + 512];
      float a3 = exact_dot(sxr, emb, k0 + 768) - en[k0 + 768];
      u64 m0 = enc_pair(a0, k0),       m1 = enc_pair(a1, k0 + 256);
      u64 m2 = enc_pair(a2, k0 + 512), m3 = enc_pair(a3, k0 + 768);
      u64 ma = m0 > m1 ? m0 : m1, mb = m2 > m3 ? m2 : m3;
      u64 mm = ma > mb ? ma : mb;
      myb = mm > myb ? mm : myb;
    }
    if (myb) atomicMax(&red, myb);
    __syncthreads();
    if (t == 0) idxa[n] = dec_idx(red);
    __syncthreads();
  }
}

// ---- gather z_q / z_q_st / indices + EMA scatter phase (R11-proven) ------
__global__ __launch_bounds__(256) void k_gather(const float* __restrict__ z_e,
                                                const float* __restrict__ emb,
                                                const int* __restrict__ idxa,
                                                float* __restrict__ out0,
                                                float* __restrict__ out1,
                                                float* __restrict__ out2,
                                                float* __restrict__ out4,
                                                float* __restrict__ out5) {
  int tid = blockIdx.x * 256 + threadIdx.x;   // 262144 = 16 b x 64 c x 256 hw4
  {   // ---- phase A: gather
    int hw4 = tid & 255;
    int c   = (tid >> 8) & 63;
    int b   = tid >> 14;
    int n0  = (b << 10) + (hw4 << 2);
    size_t off = ((size_t)b << 16) + ((size_t)c << 10) + ((size_t)hw4 << 2);
    float4 z = *(const float4*)(z_e + off);
    int i0 = idxa[n0], i1 = idxa[n0 + 1], i2 = idxa[n0 + 2], i3 = idxa[n0 + 3];
    float4 q;
    q.x = emb[(size_t)i0 * 64 + c];
    q.y = emb[(size_t)i1 * 64 + c];
    q.z = emb[(size_t)i2 * 64 + c];
    q.w = emb[(size_t)i3 * 64 + c];
    float4 st;
    st.x = z.x + (q.x - z.x);
    st.y = z.y + (q.y - z.y);
    st.z = z.z + (q.z - z.z);
    st.w = z.w + (q.w - z.w);
    *(float4*)(out2 + off) = q;
    *(float4*)(out0 + off) = st;
    if (c == 0) {
      float4 f = make_float4((float)i0, (float)i1, (float)i2, (float)i3);
      *(float4*)(out1 + n0) = f;
    }
  }
  {   // ---- phase B: scatter (4 tokens/thread, lane = channel)
    int c = tid & 63;
    int nb = (tid >> 6) * 4;
#pragma unroll
    for (int i = 0; i < 4; ++i) {
      int n = nb + i;
      int idx = idxa[n];
      int b = n >> 10, hw = n & 1023;
      float x = z_e[((size_t)b << 16) + ((size_t)c << 10) + hw];
      atomicAdd(out5 + (size_t)idx * 64 + c, OMDF * x);
      if (c == 0) atomicAdd(out4 + idx, OMDF);
    }
  }
}

// ---- new_embedding = new_embedding_avg / cs -----------------------------
__global__ __launch_bounds__(256) void k_final(const float* __restrict__ out4,
                                               const float* __restrict__ out5,
                                               const float* __restrict__ nsum,
                                               float* __restrict__ out3) {
  int tid = blockIdx.x * 256 + threadIdx.x;
  int k = tid >> 4;
  double nn  = (double)*nsum + 163.84;
  double ncs = (double)out4[k];
  double cs  = (ncs + 1e-5) / (nn + 8192.0 * 1e-5) * nn;
  float inv  = (float)(1.0 / cs);
  float4 v = ((const float4*)out5)[tid];
  v.x *= inv; v.y *= inv; v.z *= inv; v.w *= inv;
  ((float4*)out3)[tid] = v;
}

extern "C" void kernel_launch(void* const* d_in, const int* in_sizes, int n_in,
                              void* d_out, int out_size, void* d_ws, size_t ws_size,
                              hipStream_t stream) {
  const float* z_e    = (const float*)d_in[0];
  const float* emb    = (const float*)d_in[1];
  const float* cs_in  = (const float*)d_in[2];
  const float* avg_in = (const float*)d_in[3];

  float* out  = (float*)d_out;
  float* out0 = out;                    // z_q_st        1048576
  float* out1 = out0 + 1048576;         // indices(f32)  16384
  float* out2 = out1 + 16384;           // z_q           1048576
  float* out3 = out2 + 1048576;         // new_embedding 524288
  float* out4 = out3 + 524288;          // new_cluster   8192
  float* out5 = out4 + 8192;            // new_emb_avg   524288

  char* ws = (char*)d_ws;
  float* en            = (float*)(ws + EN_OFF);
  unsigned char* efrag = (unsigned char*)(ws + EFRAG_OFF);
  int* idxa            = (int*)(ws + IDX_OFF);
  u64* best1           = (u64*)(ws + BEST1_OFF);
  float* best2         = (float*)(ws + BEST2_OFF);
  float* nsum          = (float*)(ws + NSUM_OFF);
  unsigned char* zfrag = (unsigned char*)out0;   // 2 MB scratch in out0 region

  k_prep       <<<1288, 256, 0, stream>>>(emb, cs_in, avg_in, z_e, en, efrag,
                                          zfrag, out4, out5, nsum);
  k_argmin_mfma<<<2048, 256, 0, stream>>>(zfrag, efrag, en, best1, best2);
  k_resfix     <<<256,  256, 0, stream>>>(z_e, emb, en, best1, best2, idxa);
  k_gather     <<<1024, 256, 0, stream>>>(z_e, emb, idxa, out0, out1, out2,
                                          out4, out5);
  k_final      <<<512,  256, 0, stream>>>(out4, out5, nsum, out3);
}

// Round 16
// 146.696 us; speedup vs baseline: 1.2328x; 1.0543x over previous
//
#include <hip/hip_runtime.h>

// Problem: B=16,C=64,H=32,W=32 -> N=16384 tokens; K=8192 codes.
#define DECAYF 0.99f
#define OMDF   0.01f
#define TAU    3.5e-2f   // fp16 screen: ~9-sigma pairwise (sigma~3.8e-3); candidate fixup exact f32

typedef unsigned int u32;
typedef unsigned long long u64;
typedef __attribute__((ext_vector_type(8))) _Float16 f16x8;  // 8 fp16 (4 VGPRs)
typedef __attribute__((ext_vector_type(4))) float f32x4;     // MFMA 16x16 acc

// ws layout (bytes). High-water = 3702788.
// zfrag (2 MB, fp16 z_e in 16x16 A-frag order) lives in the out0 output
// region: written by k_prep, read by k_argmin, overwritten by k_gather.
// IDX overlays EFRAG head (efrag dead after k_argmin; stream-ordered).
#define EN_OFF     0              // en[8192] f32: 0.5*||e||^2
#define EFRAG_OFF  32768          // 1 MB frag-ordered fp16 emb (128 B/code)
#define IDX_OFF    32768          // i32 [16384] final indices   (overlay)
#define BEST1_OFF  2129920        // u64 [8][16384] per-(slice,token) best (enc)
#define BEST2_OFF  3178496        // f32 [8][16384] per-(slice,token) 2nd-best
#define NSUM_OFF   3702784        // f32 nsum (0.99*sum(cs_in))

__device__ __forceinline__ u64 enc_pair(float s, int idx) {
  u32 u = __float_as_uint(s);
  u = (u & 0x80000000u) ? ~u : (u | 0x80000000u);   // order-preserving
  return ((u64)u << 32) | (u32)(~idx);              // ~idx: ties -> min idx
}
__device__ __forceinline__ float dec_score(u64 e) {
  u32 u = (u32)(e >> 32);
  u = (u & 0x80000000u) ? (u & 0x7fffffffu) : ~u;
  return __uint_as_float(u);
}
__device__ __forceinline__ int dec_idx(u64 e) { return (int)(~(u32)e); }
__device__ __forceinline__ unsigned short f2h(float f) {  // f32 -> fp16 RNE
  union { _Float16 h; unsigned short u; } v;
  v.h = (_Float16)f;
  return v.u;
}
// exact f32 chain (identical FMA order across screen/fixup uses)
__device__ __forceinline__ float exact_dot(const float* __restrict__ sx,
                                           const float* __restrict__ emb, int k) {
  const float4* e = (const float4*)(emb + (size_t)k * 64);
  float a = 0.f;
#pragma unroll
  for (int q = 0; q < 16; ++q) {
    float4 v = e[q];
    a = fmaf(sx[4 * q],     v.x, a);
    a = fmaf(sx[4 * q + 1], v.y, a);
    a = fmaf(sx[4 * q + 2], v.z, a);
    a = fmaf(sx[4 * q + 3], v.w, a);
  }
  return a;
}

// ---- fused prep: [0,512) eprep | [512,1031) init | 1031 solo | [1032,1288) zprep
// zprep: 256 blocks x 64 tokens; 16.6 KB LDS
__global__ __launch_bounds__(256) void k_prep(const float* __restrict__ emb,
                                              const float* __restrict__ cs_in,
                                              const float* __restrict__ avg_in,
                                              const float* __restrict__ z_e,
                                              float* __restrict__ en,
                                              unsigned char* __restrict__ efrag,
                                              unsigned char* __restrict__ zfrag,
                                              float* __restrict__ out4,
                                              float* __restrict__ out5,
                                              float* __restrict__ nsum) {
  __shared__ float warr[4];
  __shared__ float sx[64][65];        // zprep transpose buffer (16.6 KB, padded)
  int bid = blockIdx.x;
  int t = threadIdx.x;
  if (bid < 512) {                    // ---- eprep: 131072 float4s of emb
    int tid = bid * 256 + t;
    int k = tid >> 4, q = tid & 15;   // code k, channels 4q..4q+3
    float4 v = ((const float4*)emb)[tid];
    ushort4 hv;
    hv.x = f2h(v.x); hv.y = f2h(v.y); hv.z = f2h(v.z); hv.w = f2h(v.w);
    // tile=k>>4, col=k&15, frag=q>>3, kib=(q>>1)&3, half=q&1
    size_t off = (size_t)(k >> 4) * 2048 + (size_t)(q >> 3) * 1024
               + (size_t)((q >> 1) & 3) * 256 + (size_t)(k & 15) * 16
               + (size_t)(q & 1) * 8;
    *(ushort4*)(efrag + off) = hv;
    float s = v.x * v.x + v.y * v.y + v.z * v.z + v.w * v.w;
    s += __shfl_xor(s, 1, 16);
    s += __shfl_xor(s, 2, 16);
    s += __shfl_xor(s, 4, 16);
    s += __shfl_xor(s, 8, 16);
    if (q == 0) en[k] = 0.5f * s;
  } else if (bid < 1031) {            // ---- init avg: 131072 float4s
    int tid = (bid - 512) * 256 + t;
    if (tid < 131072) {
      float4 v = ((const float4*)avg_in)[tid];
      v.x *= DECAYF; v.y *= DECAYF; v.z *= DECAYF; v.w *= DECAYF;
      ((float4*)out5)[tid] = v;
    }
  } else if (bid == 1031) {           // ---- solo: cs scale + total sum
    float s = 0.f;
#pragma unroll
    for (int q = 0; q < 8; ++q) {
      int idx = q * 256 + t;                   // 2048 float4s of cluster_size
      float4 v = ((const float4*)cs_in)[idx];
      v.x *= DECAYF; v.y *= DECAYF; v.z *= DECAYF; v.w *= DECAYF;
      ((float4*)out4)[idx] = v;
      s += v.x + v.y + v.z + v.w;              // already x0.99
    }
    s += __shfl_xor(s, 1, 64);
    s += __shfl_xor(s, 2, 64);
    s += __shfl_xor(s, 4, 64);
    s += __shfl_xor(s, 8, 64);
    s += __shfl_xor(s, 16, 64);
    s += __shfl_xor(s, 32, 64);
    if ((t & 63) == 0) warr[t >> 6] = s;
    __syncthreads();
    if (t == 0) *nsum = warr[0] + warr[1] + warr[2] + warr[3];
  } else {                            // ---- zprep: 256 blocks x 64 tokens
    int n0 = (bid - 1032) * 64;
    int b = n0 >> 10, hwb = n0 & 1023;
#pragma unroll
    for (int r = 0; r < 4; ++r) {
      int g = r * 256 + t;                     // 0..1023 float4s, coalesced
      int c = g >> 4, f4 = g & 15;
      float4 v = *(const float4*)(z_e + ((size_t)b << 16) + ((size_t)c << 10)
                                  + hwb + f4 * 4);
      sx[c][f4 * 4 + 0] = v.x;
      sx[c][f4 * 4 + 1] = v.y;
      sx[c][f4 * 4 + 2] = v.z;
      sx[c][f4 * 4 + 3] = v.w;
    }
    __syncthreads();
#pragma unroll
    for (int r = 0; r < 2; ++r) {
      int id = r * 256 + t;                    // 0..511
      int nl = id & 63, k = id >> 6;           // token-local, cell
      int n = n0 + nl;
      unsigned short u[8];
#pragma unroll
      for (int j = 0; j < 8; ++j) u[j] = f2h(sx[k * 8 + j][nl]);
      size_t off = (size_t)(n >> 4) * 2048 + (size_t)(k >> 2) * 1024
                 + (size_t)(k & 3) * 256 + (size_t)(n & 15) * 16;
      *(ushort4*)(zfrag + off)     = make_ushort4(u[0], u[1], u[2], u[3]);
      *(ushort4*)(zfrag + off + 8) = make_ushort4(u[4], u[5], u[6], u[7]);
    }
  }
}

// ---- MFMA argmin (R8-proven config, 43.2 us): 16x16x32 fp16; LDS dbuf ----
// grid 2048 = 256 token-groups (64 tokens) x 8 K-slices (1024 codes)
__global__ __launch_bounds__(256) void k_argmin_mfma(
    const unsigned char* __restrict__ zfrag,
    const unsigned char* __restrict__ efrag,
    const float* __restrict__ en, u64* __restrict__ best1,
    float* __restrict__ best2) {
  alignas(16) __shared__ unsigned char sbuf[2][8192];   // dbuf: 4 tiles each
  __shared__ float sen[1024];                           // 0.5*||e||^2 slice
  const int tb = blockIdx.x >> 3;            // token group (64 tokens)
  const int sl = blockIdx.x & 7;             // K-slice (1024 codes)
  const int wave = threadIdx.x >> 6, lane = threadIdx.x & 63;
  const int col = lane & 15, g4 = lane >> 4;
  const int token0 = tb * 64 + wave * 16;
  const int scb = sl << 10;

  // en slice -> LDS (1024 f32 = 256 float4)
  ((float4*)sen)[threadIdx.x] = ((const float4*)(en + scb))[threadIdx.x];

  // A fragments: 1 token-tile x 2 K-frags, direct vector loads from zfrag
  f16x8 a0, a1;
  {
    const unsigned char* zb = zfrag + ((size_t)(tb * 4 + wave)) * 2048
                            + (size_t)g4 * 256 + (size_t)col * 16;
    a0 = *(const f16x8*)(zb);
    a1 = *(const f16x8*)(zb + 1024);
  }
  float b1[4], b2[4];
#pragma unroll
  for (int r = 0; r < 4; ++r) { b1[r] = -3.0e38f; b2[r] = -3.0e38f; }

  const unsigned char* gbase0 = efrag + (size_t)scb * 128;   // 128 B/code
  auto stage = [&](int ib, int buf) {
    const unsigned char* g = gbase0 + (size_t)ib * 8192 + (size_t)wave * 2048;
#pragma unroll
    for (int it = 0; it < 2; ++it) {
      __builtin_amdgcn_global_load_lds(
          (const __attribute__((address_space(1))) u32*)(g + it * 1024 + lane * 16),
          (__attribute__((address_space(3))) u32*)(&sbuf[buf][wave * 2048 + it * 1024]),
          16, 0, 0);
    }
  };
  stage(0, 0);                                // prologue
  for (int ib = 0; ib < 16; ++ib) {
    __syncthreads();                          // drains vmcnt -> stage(ib) done
    if (ib < 15) stage(ib + 1, (ib + 1) & 1); // prefetch overlaps compute(ib)
    const unsigned char* sb0 = &sbuf[ib & 1][0];
#pragma unroll
    for (int ct = 0; ct < 4; ++ct) {
      const int t = ib * 4 + ct;              // 0..63 tile id in slice
      const float negen = -sen[t * 16 + col]; // this lane's code column
      f16x8 bf0 = *(const f16x8*)(sb0 + ct * 2048 + lane * 16);
      f16x8 bf1 = *(const f16x8*)(sb0 + ct * 2048 + 1024 + lane * 16);
      f32x4 acc;
#pragma unroll
      for (int r = 0; r < 4; ++r) acc[r] = negen;   // fold -0.5||e||^2 into C
      acc = __builtin_amdgcn_mfma_f32_16x16x32_f16(a0, bf0, acc, 0, 0, 0);
      acc = __builtin_amdgcn_mfma_f32_16x16x32_f16(a1, bf1, acc, 0, 0, 0);
      const u32 emb6 = (u32)(63 - t);         // tile idx in low 6 mantissa bits
#pragma unroll
      for (int r = 0; r < 4; ++r) {
        float f0 = __uint_as_float((__float_as_uint(acc[r]) & 0xFFFFFFC0u) | emb6);
        b2[r] = __builtin_amdgcn_fmed3f(f0, b1[r], b2[r]);
        b1[r] = fmaxf(b1[r], f0);
      }
    }
  }
  // reduce across the 16 code-columns (lanes within each 16-lane group)
  int mi[4];
#pragma unroll
  for (int r = 0; r < 4; ++r) mi[r] = col;
#pragma unroll
  for (int st = 1; st < 16; st <<= 1) {
#pragma unroll
    for (int r = 0; r < 4; ++r) {
      float ob1 = __shfl_xor(b1[r], st, 64);
      float ob2 = __shfl_xor(b2[r], st, 64);
      int omi = __shfl_xor(mi[r], st, 64);
      bool ogt = ob1 > b1[r];            // strict: equal -> quantized tie -> fixup
      b2[r] = fmaxf(fminf(b1[r], ob1), fmaxf(b2[r], ob2));
      mi[r] = ogt ? omi : mi[r];
      b1[r] = fmaxf(b1[r], ob1);
    }
  }
  if (col == 0) {   // lanes 0,16,32,48: 4 token-rows each; [sl][token] layout
#pragma unroll
    for (int r = 0; r < 4; ++r) {
      int token = token0 + g4 * 4 + r;        // C/D row map [m89]
      int t = 63 - (int)(__float_as_uint(b1[r]) & 63u);
      int gcode = scb + t * 16 + mi[r];
      best1[(size_t)sl * 16384 + token] = enc_pair(b1[r], gcode);
      best2[(size_t)sl * 16384 + token] = b2[r];
    }
  }
}

// ---- merged resolve + candidate fixup: block = 16 tokens, grid 1024 ------
// (4x more blocks than R14 -> serial flagged-token depth ~6 -> ~1.6)
__global__ __launch_bounds__(256) void k_resfix(const float* __restrict__ z_e,
                                                const float* __restrict__ emb,
                                                const float* __restrict__ en,
                                                const u64* __restrict__ best1,
                                                const float* __restrict__ best2,
                                                int* __restrict__ idxa) {
  __shared__ float sxr[64];
  __shared__ int flist[16];
  __shared__ float fth[16];
  __shared__ int nflag;
  __shared__ u32 fmask;
  __shared__ u64 red;
  int t = threadIdx.x;
  int n0 = blockIdx.x * 16;
  if (t == 0) nflag = 0;
  __syncthreads();
  if (t < 16) {
    int n = n0 + t;
    u64 e[8];
#pragma unroll
    for (int s = 0; s < 8; ++s) e[s] = best1[(size_t)s * 16384 + n];
    u64 top = e[0];
#pragma unroll
    for (int s = 1; s < 8; ++s) top = e[s] > top ? e[s] : top;
    float second = -3.0e38f;
#pragma unroll
    for (int s = 0; s < 8; ++s)
      second = fmaxf(second, best2[(size_t)s * 16384 + n]);
#pragma unroll
    for (int s = 0; s < 8; ++s)
      if (e[s] != top) second = fmaxf(second, dec_score(e[s]));
    idxa[n] = dec_idx(top);
    if (dec_score(top) - second < TAU) {
      int p = atomicAdd(&nflag, 1);
      flist[p] = n;
      fth[p] = dec_score(top);
    }
  }
  __syncthreads();
  int nf = nflag;
  for (int i = 0; i < nf; ++i) {
    int n = flist[i];
    float theta = fth[i] - TAU;
    if (t == 0) { fmask = 0; red = 0ull; }
    if (t < 64) {
      sxr[t] = z_e[((size_t)(n >> 10) << 16) + ((size_t)t << 10) + (n & 1023)];
    }
    __syncthreads();
    u64 myb = 0ull;
    if (t < 8) {
      u64 es = best1[(size_t)t * 16384 + n];
      if (best2[(size_t)t * 16384 + n] >= theta) atomicOr(&fmask, 1u << t);
      if (dec_score(es) >= theta) {        // candidate: exact dot
        int k = dec_idx(es);
        float a = exact_dot(sxr, emb, k) - en[k];
        myb = enc_pair(a, k);
      }
    }
    __syncthreads();
    u32 fm = fmask;
    while (fm) {                           // rare: full 1024-code slice rescan
      int s = __ffs(fm) - 1;
      fm &= fm - 1;
      int k0 = (s << 10) + t;              // 4 codes: +0,+256,+512,+768
      float a0 = exact_dot(sxr, emb, k0)       - en[k0];
      float a1 = exact_dot(sxr, emb, k0 + 256) - en[k0 + 256];
      float a2 = exact_dot(sxr, emb, k0 + 512) - en[k0 + 512];
      float a3 = exact_dot(sxr, emb, k0 + 768) - en[k0 + 768];
      u64 m0 = enc_pair(a0, k0),       m1 = enc_pair(a1, k0 + 256);
      u64 m2 = enc_pair(a2, k0 + 512), m3 = enc_pair(a3, k0 + 768);
      u64 ma = m0 > m1 ? m0 : m1, mb = m2 > m3 ? m2 : m3;
      u64 mm = ma > mb ? ma : mb;
      myb = mm > myb ? mm : myb;
    }
    if (myb) atomicMax(&red, myb);
    __syncthreads();
    if (t == 0) idxa[n] = dec_idx(red);
    __syncthreads();
  }
}

// ---- gather z_q / z_q_st / indices + EMA scatter phase (R11-proven) ------
__global__ __launch_bounds__(256) void k_gather(const float* __restrict__ z_e,
                                                const float* __restrict__ emb,
                                                const int* __restrict__ idxa,
                                                float* __restrict__ out0,
                                                float* __restrict__ out1,
                                                float* __restrict__ out2,
                                                float* __restrict__ out4,
                                                float* __restrict__ out5) {
  int tid = blockIdx.x * 256 + threadIdx.x;   // 262144 = 16 b x 64 c x 256 hw4
  {   // ---- phase A: gather
    int hw4 = tid & 255;
    int c   = (tid >> 8) & 63;
    int b   = tid >> 14;
    int n0  = (b << 10) + (hw4 << 2);
    size_t off = ((size_t)b << 16) + ((size_t)c << 10) + ((size_t)hw4 << 2);
    float4 z = *(const float4*)(z_e + off);
    int i0 = idxa[n0], i1 = idxa[n0 + 1], i2 = idxa[n0 + 2], i3 = idxa[n0 + 3];
    float4 q;
    q.x = emb[(size_t)i0 * 64 + c];
    q.y = emb[(size_t)i1 * 64 + c];
    q.z = emb[(size_t)i2 * 64 + c];
    q.w = emb[(size_t)i3 * 64 + c];
    float4 st;
    st.x = z.x + (q.x - z.x);
    st.y = z.y + (q.y - z.y);
    st.z = z.z + (q.z - z.z);
    st.w = z.w + (q.w - z.w);
    *(float4*)(out2 + off) = q;
    *(float4*)(out0 + off) = st;
    if (c == 0) {
      float4 f = make_float4((float)i0, (float)i1, (float)i2, (float)i3);
      *(float4*)(out1 + n0) = f;
    }
  }
  {   // ---- phase B: scatter (4 tokens/thread, lane = channel)
    int c = tid & 63;
    int nb = (tid >> 6) * 4;
#pragma unroll
    for (int i = 0; i < 4; ++i) {
      int n = nb + i;
      int idx = idxa[n];
      int b = n >> 10, hw = n & 1023;
      float x = z_e[((size_t)b << 16) + ((size_t)c << 10) + hw];
      atomicAdd(out5 + (size_t)idx * 64 + c, OMDF * x);
      if (c == 0) atomicAdd(out4 + idx, OMDF);
    }
  }
}

// ---- new_embedding = new_embedding_avg / cs -----------------------------
__global__ __launch_bounds__(256) void k_final(const float* __restrict__ out4,
                                               const float* __restrict__ out5,
                                               const float* __restrict__ nsum,
                                               float* __restrict__ out3) {
  int tid = blockIdx.x * 256 + threadIdx.x;
  int k = tid >> 4;
  double nn  = (double)*nsum + 163.84;
  double ncs = (double)out4[k];
  double cs  = (ncs + 1e-5) / (nn + 8192.0 * 1e-5) * nn;
  float inv  = (float)(1.0 / cs);
  float4 v = ((const float4*)out5)[tid];
  v.x *= inv; v.y *= inv; v.z *= inv; v.w *= inv;
  ((float4*)out3)[tid] = v;
}

extern "C" void kernel_launch(void* const* d_in, const int* in_sizes, int n_in,
                              void* d_out, int out_size, void* d_ws, size_t ws_size,
                              hipStream_t stream) {
  const float* z_e    = (const float*)d_in[0];
  const float* emb    = (const float*)d_in[1];
  const float* cs_in  = (const float*)d_in[2];
  const float* avg_in = (const float*)d_in[3];

  float* out  = (float*)d_out;
  float* out0 = out;                    // z_q_st        1048576
  float* out1 = out0 + 1048576;         // indices(f32)  16384
  float* out2 = out1 + 16384;           // z_q           1048576
  float* out3 = out2 + 1048576;         // new_embedding 524288
  float* out4 = out3 + 524288;          // new_cluster   8192
  float* out5 = out4 + 8192;            // new_emb_avg   524288

  char* ws = (char*)d_ws;
  float* en            = (float*)(ws + EN_OFF);
  unsigned char* efrag = (unsigned char*)(ws + EFRAG_OFF);
  int* idxa            = (int*)(ws + IDX_OFF);
  u64* best1           = (u64*)(ws + BEST1_OFF);
  float* best2         = (float*)(ws + BEST2_OFF);
  float* nsum          = (float*)(ws + NSUM_OFF);
  unsigned char* zfrag = (unsigned char*)out0;   // 2 MB scratch in out0 region

  k_prep       <<<1288, 256, 0, stream>>>(emb, cs_in, avg_in, z_e, en, efrag,
                                          zfrag, out4, out5, nsum);
  k_argmin_mfma<<<2048, 256, 0, stream>>>(zfrag, efrag, en, best1, best2);
  k_resfix     <<<1024, 256, 0, stream>>>(z_e, emb, en, best1, best2, idxa);
  k_gather     <<<1024, 256, 0, stream>>>(z_e, emb, idxa, out0, out1, out2,
                                          out4, out5);
  k_final      <<<512,  256, 0, stream>>>(out4, out5, nsum, out3);
}

// Round 17
// 145.557 us; speedup vs baseline: 1.2424x; 1.0078x over previous
//
#include <hip/hip_runtime.h>

// Problem: B=16,C=64,H=32,W=32 -> N=16384 tokens; K=8192 codes.
#define DECAYF 0.99f
#define OMDF   0.01f
#define TAU    3.5e-2f   // fp16 screen: ~9-sigma pairwise (sigma~3.8e-3); candidate fixup exact f32

typedef unsigned int u32;
typedef unsigned long long u64;
typedef __attribute__((ext_vector_type(8))) _Float16 f16x8;  // 8 fp16 (4 VGPRs)
typedef __attribute__((ext_vector_type(4))) float f32x4;     // MFMA 16x16 acc

// ws layout (bytes). High-water = 3702788.
// zfrag (2 MB, fp16 z_e in 16x16 A-frag order) lives in the out0 output
// region: written by k_prep, read by k_argmin, overwritten by k_gather.
// IDX overlays EFRAG head (efrag dead after k_argmin; stream-ordered).
#define EN_OFF     0              // en[8192] f32: 0.5*||e||^2
#define EFRAG_OFF  32768          // 1 MB frag-ordered fp16 emb (128 B/code)
#define IDX_OFF    32768          // i32 [16384] final indices   (overlay)
#define BEST1_OFF  2129920        // u64 [8][16384] per-(slice,token) best (enc)
#define BEST2_OFF  3178496        // f32 [8][16384] per-(slice,token) 2nd-best
#define NSUM_OFF   3702784        // f32 nsum (0.99*sum(cs_in))

__device__ __forceinline__ u64 enc_pair(float s, int idx) {
  u32 u = __float_as_uint(s);
  u = (u & 0x80000000u) ? ~u : (u | 0x80000000u);   // order-preserving
  return ((u64)u << 32) | (u32)(~idx);              // ~idx: ties -> min idx
}
__device__ __forceinline__ float dec_score(u64 e) {
  u32 u = (u32)(e >> 32);
  u = (u & 0x80000000u) ? (u & 0x7fffffffu) : ~u;
  return __uint_as_float(u);
}
__device__ __forceinline__ int dec_idx(u64 e) { return (int)(~(u32)e); }
__device__ __forceinline__ unsigned short f2h(float f) {  // f32 -> fp16 RNE
  union { _Float16 h; unsigned short u; } v;
  v.h = (_Float16)f;
  return v.u;
}
// exact f32 chain (identical FMA order across screen/fixup uses)
__device__ __forceinline__ float exact_dot(const float* __restrict__ sx,
                                           const float* __restrict__ emb, int k) {
  const float4* e = (const float4*)(emb + (size_t)k * 64);
  float a = 0.f;
#pragma unroll
  for (int q = 0; q < 16; ++q) {
    float4 v = e[q];
    a = fmaf(sx[4 * q],     v.x, a);
    a = fmaf(sx[4 * q + 1], v.y, a);
    a = fmaf(sx[4 * q + 2], v.z, a);
    a = fmaf(sx[4 * q + 3], v.w, a);
  }
  return a;
}

// ---- fused prep: [0,512) eprep | [512,1031) init | 1031 solo | [1032,1288) zprep
// zprep: 256 blocks x 64 tokens; 16.6 KB LDS
__global__ __launch_bounds__(256) void k_prep(const float* __restrict__ emb,
                                              const float* __restrict__ cs_in,
                                              const float* __restrict__ avg_in,
                                              const float* __restrict__ z_e,
                                              float* __restrict__ en,
                                              unsigned char* __restrict__ efrag,
                                              unsigned char* __restrict__ zfrag,
                                              float* __restrict__ out4,
                                              float* __restrict__ out5,
                                              float* __restrict__ nsum) {
  __shared__ float warr[4];
  __shared__ float sx[64][65];        // zprep transpose buffer (16.6 KB, padded)
  int bid = blockIdx.x;
  int t = threadIdx.x;
  if (bid < 512) {                    // ---- eprep: 131072 float4s of emb
    int tid = bid * 256 + t;
    int k = tid >> 4, q = tid & 15;   // code k, channels 4q..4q+3
    float4 v = ((const float4*)emb)[tid];
    ushort4 hv;
    hv.x = f2h(v.x); hv.y = f2h(v.y); hv.z = f2h(v.z); hv.w = f2h(v.w);
    // tile=k>>4, col=k&15, frag=q>>3, kib=(q>>1)&3, half=q&1
    size_t off = (size_t)(k >> 4) * 2048 + (size_t)(q >> 3) * 1024
               + (size_t)((q >> 1) & 3) * 256 + (size_t)(k & 15) * 16
               + (size_t)(q & 1) * 8;
    *(ushort4*)(efrag + off) = hv;
    float s = v.x * v.x + v.y * v.y + v.z * v.z + v.w * v.w;
    s += __shfl_xor(s, 1, 16);
    s += __shfl_xor(s, 2, 16);
    s += __shfl_xor(s, 4, 16);
    s += __shfl_xor(s, 8, 16);
    if (q == 0) en[k] = 0.5f * s;
  } else if (bid < 1031) {            // ---- init avg: 131072 float4s
    int tid = (bid - 512) * 256 + t;
    if (tid < 131072) {
      float4 v = ((const float4*)avg_in)[tid];
      v.x *= DECAYF; v.y *= DECAYF; v.z *= DECAYF; v.w *= DECAYF;
      ((float4*)out5)[tid] = v;
    }
  } else if (bid == 1031) {           // ---- solo: cs scale + total sum
    float s = 0.f;
#pragma unroll
    for (int q = 0; q < 8; ++q) {
      int idx = q * 256 + t;                   // 2048 float4s of cluster_size
      float4 v = ((const float4*)cs_in)[idx];
      v.x *= DECAYF; v.y *= DECAYF; v.z *= DECAYF; v.w *= DECAYF;
      ((float4*)out4)[idx] = v;
      s += v.x + v.y + v.z + v.w;              // already x0.99
    }
    s += __shfl_xor(s, 1, 64);
    s += __shfl_xor(s, 2, 64);
    s += __shfl_xor(s, 4, 64);
    s += __shfl_xor(s, 8, 64);
    s += __shfl_xor(s, 16, 64);
    s += __shfl_xor(s, 32, 64);
    if ((t & 63) == 0) warr[t >> 6] = s;
    __syncthreads();
    if (t == 0) *nsum = warr[0] + warr[1] + warr[2] + warr[3];
  } else {                            // ---- zprep: 256 blocks x 64 tokens
    int n0 = (bid - 1032) * 64;
    int b = n0 >> 10, hwb = n0 & 1023;
#pragma unroll
    for (int r = 0; r < 4; ++r) {
      int g = r * 256 + t;                     // 0..1023 float4s, coalesced
      int c = g >> 4, f4 = g & 15;
      float4 v = *(const float4*)(z_e + ((size_t)b << 16) + ((size_t)c << 10)
                                  + hwb + f4 * 4);
      sx[c][f4 * 4 + 0] = v.x;
      sx[c][f4 * 4 + 1] = v.y;
      sx[c][f4 * 4 + 2] = v.z;
      sx[c][f4 * 4 + 3] = v.w;
    }
    __syncthreads();
#pragma unroll
    for (int r = 0; r < 2; ++r) {
      int id = r * 256 + t;                    // 0..511
      int nl = id & 63, k = id >> 6;           // token-local, cell
      int n = n0 + nl;
      unsigned short u[8];
#pragma unroll
      for (int j = 0; j < 8; ++j) u[j] = f2h(sx[k * 8 + j][nl]);
      size_t off = (size_t)(n >> 4) * 2048 + (size_t)(k >> 2) * 1024
                 + (size_t)(k & 3) * 256 + (size_t)(n & 15) * 16;
      *(ushort4*)(zfrag + off)     = make_ushort4(u[0], u[1], u[2], u[3]);
      *(ushort4*)(zfrag + off + 8) = make_ushort4(u[4], u[5], u[6], u[7]);
    }
  }
}

// ---- MFMA argmin (R8-proven config + T5 setprio): 16x16x32 fp16; LDS dbuf
// grid 2048 = 256 token-groups (64 tokens) x 8 K-slices (1024 codes)
// T5: 8 independent blocks/CU at different phases -> scheduler role-split,
// setprio(1) around the MFMA pair biases issue toward matrix-feeding waves.
__global__ __launch_bounds__(256) void k_argmin_mfma(
    const unsigned char* __restrict__ zfrag,
    const unsigned char* __restrict__ efrag,
    const float* __restrict__ en, u64* __restrict__ best1,
    float* __restrict__ best2) {
  alignas(16) __shared__ unsigned char sbuf[2][8192];   // dbuf: 4 tiles each
  __shared__ float sen[1024];                           // 0.5*||e||^2 slice
  const int tb = blockIdx.x >> 3;            // token group (64 tokens)
  const int sl = blockIdx.x & 7;             // K-slice (1024 codes)
  const int wave = threadIdx.x >> 6, lane = threadIdx.x & 63;
  const int col = lane & 15, g4 = lane >> 4;
  const int token0 = tb * 64 + wave * 16;
  const int scb = sl << 10;

  // en slice -> LDS (1024 f32 = 256 float4)
  ((float4*)sen)[threadIdx.x] = ((const float4*)(en + scb))[threadIdx.x];

  // A fragments: 1 token-tile x 2 K-frags, direct vector loads from zfrag
  f16x8 a0, a1;
  {
    const unsigned char* zb = zfrag + ((size_t)(tb * 4 + wave)) * 2048
                            + (size_t)g4 * 256 + (size_t)col * 16;
    a0 = *(const f16x8*)(zb);
    a1 = *(const f16x8*)(zb + 1024);
  }
  float b1[4], b2[4];
#pragma unroll
  for (int r = 0; r < 4; ++r) { b1[r] = -3.0e38f; b2[r] = -3.0e38f; }

  const unsigned char* gbase0 = efrag + (size_t)scb * 128;   // 128 B/code
  auto stage = [&](int ib, int buf) {
    const unsigned char* g = gbase0 + (size_t)ib * 8192 + (size_t)wave * 2048;
#pragma unroll
    for (int it = 0; it < 2; ++it) {
      __builtin_amdgcn_global_load_lds(
          (const __attribute__((address_space(1))) u32*)(g + it * 1024 + lane * 16),
          (__attribute__((address_space(3))) u32*)(&sbuf[buf][wave * 2048 + it * 1024]),
          16, 0, 0);
    }
  };
  stage(0, 0);                                // prologue
  for (int ib = 0; ib < 16; ++ib) {
    __syncthreads();                          // drains vmcnt -> stage(ib) done
    if (ib < 15) stage(ib + 1, (ib + 1) & 1); // prefetch overlaps compute(ib)
    const unsigned char* sb0 = &sbuf[ib & 1][0];
#pragma unroll
    for (int ct = 0; ct < 4; ++ct) {
      const int t = ib * 4 + ct;              // 0..63 tile id in slice
      const float negen = -sen[t * 16 + col]; // this lane's code column
      f16x8 bf0 = *(const f16x8*)(sb0 + ct * 2048 + lane * 16);
      f16x8 bf1 = *(const f16x8*)(sb0 + ct * 2048 + 1024 + lane * 16);
      f32x4 acc;
#pragma unroll
      for (int r = 0; r < 4; ++r) acc[r] = negen;   // fold -0.5||e||^2 into C
      __builtin_amdgcn_s_setprio(1);          // T5: favor MFMA-entering wave
      acc = __builtin_amdgcn_mfma_f32_16x16x32_f16(a0, bf0, acc, 0, 0, 0);
      acc = __builtin_amdgcn_mfma_f32_16x16x32_f16(a1, bf1, acc, 0, 0, 0);
      __builtin_amdgcn_s_setprio(0);
      const u32 emb6 = (u32)(63 - t);         // tile idx in low 6 mantissa bits
#pragma unroll
      for (int r = 0; r < 4; ++r) {
        float f0 = __uint_as_float((__float_as_uint(acc[r]) & 0xFFFFFFC0u) | emb6);
        b2[r] = __builtin_amdgcn_fmed3f(f0, b1[r], b2[r]);
        b1[r] = fmaxf(b1[r], f0);
      }
    }
  }
  // reduce across the 16 code-columns (lanes within each 16-lane group)
  int mi[4];
#pragma unroll
  for (int r = 0; r < 4; ++r) mi[r] = col;
#pragma unroll
  for (int st = 1; st < 16; st <<= 1) {
#pragma unroll
    for (int r = 0; r < 4; ++r) {
      float ob1 = __shfl_xor(b1[r], st, 64);
      float ob2 = __shfl_xor(b2[r], st, 64);
      int omi = __shfl_xor(mi[r], st, 64);
      bool ogt = ob1 > b1[r];            // strict: equal -> quantized tie -> fixup
      b2[r] = fmaxf(fminf(b1[r], ob1), fmaxf(b2[r], ob2));
      mi[r] = ogt ? omi : mi[r];
      b1[r] = fmaxf(b1[r], ob1);
    }
  }
  if (col == 0) {   // lanes 0,16,32,48: 4 token-rows each; [sl][token] layout
#pragma unroll
    for (int r = 0; r < 4; ++r) {
      int token = token0 + g4 * 4 + r;        // C/D row map [m89]
      int t = 63 - (int)(__float_as_uint(b1[r]) & 63u);
      int gcode = scb + t * 16 + mi[r];
      best1[(size_t)sl * 16384 + token] = enc_pair(b1[r], gcode);
      best2[(size_t)sl * 16384 + token] = b2[r];
    }
  }
}

// ---- merged resolve + candidate fixup: block = 16 tokens, grid 1024 ------
__global__ __launch_bounds__(256) void k_resfix(const float* __restrict__ z_e,
                                                const float* __restrict__ emb,
                                                const float* __restrict__ en,
                                                const u64* __restrict__ best1,
                                                const float* __restrict__ best2,
                                                int* __restrict__ idxa) {
  __shared__ float sxr[64];
  __shared__ int flist[16];
  __shared__ float fth[16];
  __shared__ int nflag;
  __shared__ u32 fmask;
  __shared__ u64 red;
  int t = threadIdx.x;
  int n0 = blockIdx.x * 16;
  if (t == 0) nflag = 0;
  __syncthreads();
  if (t < 16) {
    int n = n0 + t;
    u64 e[8];
#pragma unroll
    for (int s = 0; s < 8; ++s) e[s] = best1[(size_t)s * 16384 + n];
    u64 top = e[0];
#pragma unroll
    for (int s = 1; s < 8; ++s) top = e[s] > top ? e[s] : top;
    float second = -3.0e38f;
#pragma unroll
    for (int s = 0; s < 8; ++s)
      second = fmaxf(second, best2[(size_t)s * 16384 + n]);
#pragma unroll
    for (int s = 0; s < 8; ++s)
      if (e[s] != top) second = fmaxf(second, dec_score(e[s]));
    idxa[n] = dec_idx(top);
    if (dec_score(top) - second < TAU) {
      int p = atomicAdd(&nflag, 1);
      flist[p] = n;
      fth[p] = dec_score(top);
    }
  }
  __syncthreads();
  int nf = nflag;
  for (int i = 0; i < nf; ++i) {
    int n = flist[i];
    float theta = fth[i] - TAU;
    if (t == 0) { fmask = 0; red = 0ull; }
    if (t < 64) {
      sxr[t] = z_e[((size_t)(n >> 10) << 16) + ((size_t)t << 10) + (n & 1023)];
    }
    __syncthreads();
    u64 myb = 0ull;
    if (t < 8) {
      u64 es = best1[(size_t)t * 16384 + n];
      if (best2[(size_t)t * 16384 + n] >= theta) atomicOr(&fmask, 1u << t);
      if (dec_score(es) >= theta) {        // candidate: exact dot
        int k = dec_idx(es);
        float a = exact_dot(sxr, emb, k) - en[k];
        myb = enc_pair(a, k);
      }
    }
    __syncthreads();
    u32 fm = fmask;
    while (fm) {                           // rare: full 1024-code slice rescan
      int s = __ffs(fm) - 1;
      fm &= fm - 1;
      int k0 = (s << 10) + t;              // 4 codes: +0,+256,+512,+768
      float a0 = exact_dot(sxr, emb, k0)       - en[k0];
      float a1 = exact_dot(sxr, emb, k0 + 256) - en[k0 + 256];
      float a2 = exact_dot(sxr, emb, k0 + 512) - en[k0 + 512];
      float a3 = exact_dot(sxr, emb, k0 + 768) - en[k0 + 768];
      u64 m0 = enc_pair(a0, k0),       m1 = enc_pair(a1, k0 + 256);
      u64 m2 = enc_pair(a2, k0 + 512), m3 = enc_pair(a3, k0 + 768);
      u64 ma = m0 > m1 ? m0 : m1, mb = m2 > m3 ? m2 : m3;
      u64 mm = ma > mb ? ma : mb;
      myb = mm > myb ? mm : myb;
    }
    if (myb) atomicMax(&red, myb);
    __syncthreads();
    if (t == 0) idxa[n] = dec_idx(red);
    __syncthreads();
  }
}

// ---- gather z_q / z_q_st / indices + EMA scatter phase (R11-proven) ------
__global__ __launch_bounds__(256) void k_gather(const float* __restrict__ z_e,
                                                const float* __restrict__ emb,
                                                const int* __restrict__ idxa,
                                                float* __restrict__ out0,
                                                float* __restrict__ out1,
                                                float* __restrict__ out2,
                                                float* __restrict__ out4,
                                                float* __restrict__ out5) {
  int tid = blockIdx.x * 256 + threadIdx.x;   // 262144 = 16 b x 64 c x 256 hw4
  {   // ---- phase A: gather
    int hw4 = tid & 255;
    int c   = (tid >> 8) & 63;
    int b   = tid >> 14;
    int n0  = (b << 10) + (hw4 << 2);
    size_t off = ((size_t)b << 16) + ((size_t)c << 10) + ((size_t)hw4 << 2);
    float4 z = *(const float4*)(z_e + off);
    int i0 = idxa[n0], i1 = idxa[n0 + 1], i2 = idxa[n0 + 2], i3 = idxa[n0 + 3];
    float4 q;
    q.x = emb[(size_t)i0 * 64 + c];
    q.y = emb[(size_t)i1 * 64 + c];
    q.z = emb[(size_t)i2 * 64 + c];
    q.w = emb[(size_t)i3 * 64 + c];
    float4 st;
    st.x = z.x + (q.x - z.x);
    st.y = z.y + (q.y - z.y);
    st.z = z.z + (q.z - z.z);
    st.w = z.w + (q.w - z.w);
    *(float4*)(out2 + off) = q;
    *(float4*)(out0 + off) = st;
    if (c == 0) {
      float4 f = make_float4((float)i0, (float)i1, (float)i2, (float)i3);
      *(float4*)(out1 + n0) = f;
    }
  }
  {   // ---- phase B: scatter (4 tokens/thread, lane = channel)
    int c = tid & 63;
    int nb = (tid >> 6) * 4;
#pragma unroll
    for (int i = 0; i < 4; ++i) {
      int n = nb + i;
      int idx = idxa[n];
      int b = n >> 10, hw = n & 1023;
      float x = z_e[((size_t)b << 16) + ((size_t)c << 10) + hw];
      atomicAdd(out5 + (size_t)idx * 64 + c, OMDF * x);
      if (c == 0) atomicAdd(out4 + idx, OMDF);
    }
  }
}

// ---- new_embedding = new_embedding_avg / cs -----------------------------
__global__ __launch_bounds__(256) void k_final(const float* __restrict__ out4,
                                               const float* __restrict__ out5,
                                               const float* __restrict__ nsum,
                                               float* __restrict__ out3) {
  int tid = blockIdx.x * 256 + threadIdx.x;
  int k = tid >> 4;
  double nn  = (double)*nsum + 163.84;
  double ncs = (double)out4[k];
  double cs  = (ncs + 1e-5) / (nn + 8192.0 * 1e-5) * nn;
  float inv  = (float)(1.0 / cs);
  float4 v = ((const float4*)out5)[tid];
  v.x *= inv; v.y *= inv; v.z *= inv; v.w *= inv;
  ((float4*)out3)[tid] = v;
}

extern "C" void kernel_launch(void* const* d_in, const int* in_sizes, int n_in,
                              void* d_out, int out_size, void* d_ws, size_t ws_size,
                              hipStream_t stream) {
  const float* z_e    = (const float*)d_in[0];
  const float* emb    = (const float*)d_in[1];
  const float* cs_in  = (const float*)d_in[2];
  const float* avg_in = (const float*)d_in[3];

  float* out  = (float*)d_out;
  float* out0 = out;                    // z_q_st        1048576
  float* out1 = out0 + 1048576;         // indices(f32)  16384
  float* out2 = out1 + 16384;           // z_q           1048576
  float* out3 = out2 + 1048576;         // new_embedding 524288
  float* out4 = out3 + 524288;          // new_cluster   8192
  float* out5 = out4 + 8192;            // new_emb_avg   524288

  char* ws = (char*)d_ws;
  float* en            = (float*)(ws + EN_OFF);
  unsigned char* efrag = (unsigned char*)(ws + EFRAG_OFF);
  int* idxa            = (int*)(ws + IDX_OFF);
  u64* best1           = (u64*)(ws + BEST1_OFF);
  float* best2         = (float*)(ws + BEST2_OFF);
  float* nsum          = (float*)(ws + NSUM_OFF);
  unsigned char* zfrag = (unsigned char*)out0;   // 2 MB scratch in out0 region

  k_prep       <<<1288, 256, 0, stream>>>(emb, cs_in, avg_in, z_e, en, efrag,
                                          zfrag, out4, out5, nsum);
  k_argmin_mfma<<<2048, 256, 0, stream>>>(zfrag, efrag, en, best1, best2);
  k_resfix     <<<1024, 256, 0, stream>>>(z_e, emb, en, best1, best2, idxa);
  k_gather     <<<1024, 256, 0, stream>>>(z_e, emb, idxa, out0, out1, out2,
                                          out4, out5);
  k_final      <<<512,  256, 0, stream>>>(out4, out5, nsum, out3);
}